// Round 2
// baseline (430.422 us; speedup 1.0000x reference)
//
#include <hip/hip_runtime.h>
#include <math.h>

#define NN 2048
#define KN 30

typedef __bf16 bf16x8 __attribute__((ext_vector_type(8)));
typedef float f32x4 __attribute__((ext_vector_type(4)));
typedef unsigned short u16x8 __attribute__((ext_vector_type(8)));
typedef unsigned short u16x4 __attribute__((ext_vector_type(4)));

__device__ __forceinline__ unsigned short f2bf(float f) {
  unsigned u = __builtin_bit_cast(unsigned, f);
  u += 0x7FFFu + ((u >> 16) & 1u);
  return (unsigned short)(u >> 16);
}

__device__ __forceinline__ float gelu_f(float x) {
  return 0.5f * x * (1.0f + erff(x * 0.70710678118654752f));
}

// mask read per detected mode: 1=uint8, 2=float32, 0=int32
__device__ __forceinline__ bool rdmask(const void* p, int i, int mode) {
  if (mode == 1) return ((const unsigned char*)p)[i] != 0;
  if (mode == 2) return ((const float*)p)[i] != 0.0f;
  return ((const int*)p)[i] != 0;
}

// A-fragment: lane (l&15) = row within 16-row tile; 8 contiguous bf16 along K
// starting at k = 32*s + 8*(l>>4). LDS rows XOR-swizzled by ((row&7)<<4).
__device__ __forceinline__ bf16x8 ld_afrag(const char* base, int row, int rowstride, int s, int g) {
  int byte = row * rowstride + s * 64 + g * 16;
  byte ^= (row & 7) << 4;
  u16x8 u = *(const u16x8*)(base + byte);
  return __builtin_bit_cast(bf16x8, u);
}

__device__ __forceinline__ bf16x8 ld_bfrag(const u16x8* __restrict__ pw, int s, int t, int NT, int lane) {
  u16x8 u = pw[(s * NT + t) * 64 + lane];
  return __builtin_bit_cast(bf16x8, u);
}

// ---------------------------------------------------------------------------
// K0: pack 5 weight matrices f32 -> bf16, fragment-major.
// p = ((s*NT + t)*64 + l)*8 + j  holds  W[32*s + 8*(l>>4) + j][16*t + (l&15)]
// Ranges (bf16 elems): m0 [0,65536) m1 [65536,81920) m2 [81920,98304)
//                      f0 [98304,163840) f1 [163840,229376)
// ---------------------------------------------------------------------------
__global__ void k0_pack(const float* __restrict__ Wm0, const float* __restrict__ Wm1,
                        const float* __restrict__ Wm2, const float* __restrict__ Wf0,
                        const float* __restrict__ Wf1, unsigned short* __restrict__ dst) {
  int i = blockIdx.x * 256 + threadIdx.x;
  if (i >= 229376) return;
  const float* W;
  int base, Nc;
  if (i < 65536)       { W = Wm0; base = 0;      Nc = 128; }
  else if (i < 81920)  { W = Wm1; base = 65536;  Nc = 128; }
  else if (i < 98304)  { W = Wm2; base = 81920;  Nc = 128; }
  else if (i < 163840) { W = Wf0; base = 98304;  Nc = 512; }
  else                 { W = Wf1; base = 163840; Nc = 128; }
  int NT = Nc >> 4;
  int p = i - base;
  int j = p & 7;
  int l = (p >> 3) & 63;
  int rest = p >> 9;
  int t = rest % NT;
  int s = rest / NT;
  int kk = 32 * s + 8 * (l >> 4) + j;
  int c = 16 * t + (l & 15);
  dst[i] = f2bf(W[kk * Nc + c]);
}

// ---------------------------------------------------------------------------
// KD: detect mask storage width. Scans first 245760 bytes of edge_mask
// (bernoulli 0.9). byte-fraction: uint8 ~0.9, int32 ~0.225, f32 ~0.45.
// mode: 1=uint8, 0=int32, 2=float32  -> flag
// ---------------------------------------------------------------------------
__global__ void kd_detect(const unsigned char* __restrict__ m, int* __restrict__ flag) {
  __shared__ int sB[256], sI[256], sF[256];
  int cB = 0, cI = 0, cF = 0;
  for (int i = threadIdx.x * 16; i < 245760; i += 256 * 16) {
    uint4 v = *(const uint4*)(m + i);
    cB += __popc(v.x & 0x01010101u) + __popc(v.y & 0x01010101u) +
          __popc(v.z & 0x01010101u) + __popc(v.w & 0x01010101u);
    cI += (v.x == 1u) + (v.y == 1u) + (v.z == 1u) + (v.w == 1u);
    cF += (v.x == 0x3F800000u) + (v.y == 0x3F800000u) +
          (v.z == 0x3F800000u) + (v.w == 0x3F800000u);
  }
  sB[threadIdx.x] = cB; sI[threadIdx.x] = cI; sF[threadIdx.x] = cF;
  __syncthreads();
  for (int st = 128; st > 0; st >>= 1) {
    if (threadIdx.x < st) {
      sB[threadIdx.x] += sB[threadIdx.x + st];
      sI[threadIdx.x] += sI[threadIdx.x + st];
      sF[threadIdx.x] += sF[threadIdx.x + st];
    }
    __syncthreads();
  }
  if (threadIdx.x == 0) {
    int mode;
    if (sB[0] > 122880) mode = 1;          // >50% nonzero bytes -> uint8
    else if (sF[0] > sI[0]) mode = 2;      // float32 1.0f pattern dominates
    else mode = 0;                          // int32
    *flag = mode;
  }
}

// ---------------------------------------------------------------------------
// K1: per-WG = 2 nodes (60 edges + 4 pad rows). A-tile [64][384] bf16
// (Vj|E|Es); Vi handled as per-node f32 matvec vb = Vi @ Wm0[0:128].
// 3-layer MLP via MFMA; fragment-level masked row-sum -> Msum.
// LDS: stage [0,49152); h0 overlays [0,16384); h1 [16384,32768);
//      vb f32[2][128] @49152; em f32[64] @50176. Total 50432 B.
// ---------------------------------------------------------------------------
__global__ __launch_bounds__(256, 2) void k1_edge_mlp(
    const float* __restrict__ Vnew, const float* __restrict__ Vold,
    const float* __restrict__ E, const float* __restrict__ S,
    const int* __restrict__ Kidx, const void* __restrict__ emask,
    const void* __restrict__ amask,
    const float* __restrict__ Wm0f,
    const u16x8* __restrict__ pWm0, const u16x8* __restrict__ pWm1,
    const u16x8* __restrict__ pWm2,
    const float* __restrict__ bm0, const float* __restrict__ bm1,
    const float* __restrict__ bm2,
    const int* __restrict__ modeflag,
    float* __restrict__ Msum) {
  extern __shared__ char smem[];
  float* vb = (float*)(smem + 49152);      // [2][128]
  float* em_lds = (float*)(smem + 50176);  // [64]
  const int tid = threadIdx.x;
  const int p = blockIdx.x;
  const int z = (2 * p) / NN;
  const int n0 = (2 * p) % NN;
  const int mode = *modeflag;

  // ---- stage A tile [64][384] bf16 (swizzled): q0=Vj q1=E q2=Es; q3 -> em ----
  {
    int row = tid >> 2, q = tid & 3;
    if (q == 3) {
      if (row < 60) {
        int ln = row / 30;
        int eidx = (z * NN + n0 + ln) * KN + (row - 30 * ln);
        em_lds[row] = rdmask(emask, eidx, mode) ? 1.0f : 0.0f;
      }
    } else {
      const float* src = nullptr;
      if (row < 60) {
        int ln = row / 30;
        int n = n0 + ln;
        int k = row - 30 * ln;
        int eidx = (z * NN + n) * KN + k;
        int kidx = Kidx[eidx];
        bool am = rdmask(amask, eidx, mode);
        if (q == 0)      src = (am ? Vnew : Vold) + (z * NN + kidx) * 128;
        else if (q == 1) src = E + (long)eidx * 128;
        else             src = am ? (S + (z * NN + kidx) * 128) : nullptr;
      }
      char* arow = smem + row * 768;
#pragma unroll 8
      for (int i = 0; i < 32; ++i) {
        float4 v = src ? ((const float4*)src)[i] : make_float4(0.f, 0.f, 0.f, 0.f);
        u16x4 h;
        h[0] = f2bf(v.x); h[1] = f2bf(v.y); h[2] = f2bf(v.z); h[3] = f2bf(v.w);
        int byte = q * 256 + i * 8;
        byte ^= (row & 7) << 4;
        *(u16x4*)(arow + byte) = h;
      }
    }
  }

  // ---- vb[node][col] = Vnew[node] . Wm0[0:128][col]  (f32 exact) ----
  {
    int nd = tid >> 7, col = tid & 127;
    const float* vi = Vnew + (z * NN + n0 + nd) * 128;
    float acc = 0.f;
#pragma unroll 4
    for (int k = 0; k < 128; ++k) acc = fmaf(vi[k], Wm0f[k * 128 + col], acc);
    vb[nd * 128 + col] = acc;
  }
  __syncthreads();

  const int w = tid >> 6, l = tid & 63;
  const int r = l & 15, g = l >> 4;
  float bb0[2], bb1[2], bb2[2];
#pragma unroll
  for (int tt = 0; tt < 2; ++tt) {
    int col = 32 * w + 16 * tt + r;
    bb0[tt] = bm0[col]; bb1[tt] = bm1[col]; bb2[tt] = bm2[col];
  }
  const f32x4 zf = {0.f, 0.f, 0.f, 0.f};

  // ---- layer 0: [64x384] @ Wm0[128:512][128]  (B-frag s offset +4) ----
  f32x4 acc[4][2];
#pragma unroll
  for (int mt = 0; mt < 4; ++mt)
#pragma unroll
    for (int tt = 0; tt < 2; ++tt) acc[mt][tt] = zf;
  for (int s = 0; s < 12; ++s) {
    bf16x8 a[4];
#pragma unroll
    for (int mt = 0; mt < 4; ++mt) a[mt] = ld_afrag(smem, 16 * mt + r, 768, s, g);
#pragma unroll
    for (int tt = 0; tt < 2; ++tt) {
      bf16x8 b = ld_bfrag(pWm0, s + 4, 2 * w + tt, 8, l);
#pragma unroll
      for (int mt = 0; mt < 4; ++mt)
        acc[mt][tt] = __builtin_amdgcn_mfma_f32_16x16x32_bf16(a[mt], b, acc[mt][tt], 0, 0, 0);
    }
  }
  __syncthreads();  // all waves done reading A tile
  char* h0 = smem;  // [64][128] bf16, swizzled, rowstride 256
#pragma unroll
  for (int mt = 0; mt < 4; ++mt)
#pragma unroll
    for (int tt = 0; tt < 2; ++tt)
#pragma unroll
      for (int j = 0; j < 4; ++j) {
        int row = 16 * mt + 4 * g + j;
        int col = 32 * w + 16 * tt + r;
        float v = 0.f;
        if (row < 60)
          v = gelu_f(acc[mt][tt][j] + vb[(row >= 30) * 128 + col] + bb0[tt]);
        int byte = row * 256 + col * 2;
        byte ^= (row & 7) << 4;
        *(unsigned short*)(h0 + byte) = f2bf(v);
      }
  __syncthreads();

  // ---- layer 1: [64x128] @ Wm1[128x128] ----
  char* h1 = smem + 16384;
  {
    f32x4 acc1[4][2];
#pragma unroll
    for (int mt = 0; mt < 4; ++mt)
#pragma unroll
      for (int tt = 0; tt < 2; ++tt) acc1[mt][tt] = zf;
#pragma unroll
    for (int s = 0; s < 4; ++s) {
      bf16x8 a[4];
#pragma unroll
      for (int mt = 0; mt < 4; ++mt) a[mt] = ld_afrag(h0, 16 * mt + r, 256, s, g);
#pragma unroll
      for (int tt = 0; tt < 2; ++tt) {
        bf16x8 b = ld_bfrag(pWm1, s, 2 * w + tt, 8, l);
#pragma unroll
        for (int mt = 0; mt < 4; ++mt)
          acc1[mt][tt] = __builtin_amdgcn_mfma_f32_16x16x32_bf16(a[mt], b, acc1[mt][tt], 0, 0, 0);
      }
    }
#pragma unroll
    for (int mt = 0; mt < 4; ++mt)
#pragma unroll
      for (int tt = 0; tt < 2; ++tt)
#pragma unroll
        for (int j = 0; j < 4; ++j) {
          int row = 16 * mt + 4 * g + j;
          int col = 32 * w + 16 * tt + r;
          float v = gelu_f(acc1[mt][tt][j] + bb1[tt]);
          int byte = row * 256 + col * 2;
          byte ^= (row & 7) << 4;
          *(unsigned short*)(h1 + byte) = f2bf(v);
        }
  }
  __syncthreads();

  // ---- layer 2: [64x128] @ Wm2[128x128]; fragment-level masked node-sum ----
  {
    f32x4 acc2[4][2];
#pragma unroll
    for (int mt = 0; mt < 4; ++mt)
#pragma unroll
      for (int tt = 0; tt < 2; ++tt) acc2[mt][tt] = zf;
#pragma unroll
    for (int s = 0; s < 4; ++s) {
      bf16x8 a[4];
#pragma unroll
      for (int mt = 0; mt < 4; ++mt) a[mt] = ld_afrag(h1, 16 * mt + r, 256, s, g);
#pragma unroll
      for (int tt = 0; tt < 2; ++tt) {
        bf16x8 b = ld_bfrag(pWm2, s, 2 * w + tt, 8, l);
#pragma unroll
        for (int mt = 0; mt < 4; ++mt)
          acc2[mt][tt] = __builtin_amdgcn_mfma_f32_16x16x32_bf16(a[mt], b, acc2[mt][tt], 0, 0, 0);
      }
    }
    float s0[2] = {0.f, 0.f}, s1[2] = {0.f, 0.f};
#pragma unroll
    for (int mt = 0; mt < 4; ++mt)
#pragma unroll
      for (int tt = 0; tt < 2; ++tt)
#pragma unroll
        for (int j = 0; j < 4; ++j) {
          int row = 16 * mt + 4 * g + j;
          if (row < 60) {
            float v = (acc2[mt][tt][j] + bb2[tt]) * em_lds[row];
            if (row < 30) s0[tt] += v; else s1[tt] += v;
          }
        }
#pragma unroll
    for (int tt = 0; tt < 2; ++tt) {
      s0[tt] += __shfl_xor(s0[tt], 16); s0[tt] += __shfl_xor(s0[tt], 32);
      s1[tt] += __shfl_xor(s1[tt], 16); s1[tt] += __shfl_xor(s1[tt], 32);
    }
    if (g == 0) {
#pragma unroll
      for (int tt = 0; tt < 2; ++tt)
        Msum[(z * NN + n0) * 128 + 32 * w + 16 * tt + r] = s0[tt];
    } else if (g == 1) {
#pragma unroll
      for (int tt = 0; tt < 2; ++tt)
        Msum[(z * NN + n0 + 1) * 128 + 32 * w + 16 * tt + r] = s1[tt];
    }
  }
}

// ---------------------------------------------------------------------------
// K2: 32 nodes/WG. LN1 -> FFN (MFMA vs packed W_f0/W_f1) -> LN2 -> out.
// LDS: V1f f32 [32][128] @0 (16K); A1 bf16 [32][128] @16K (8K, swz);
//      hb bf16 [32][512] @24K (32K, swz); op f32 [32][128] @16K (reuse).
// ---------------------------------------------------------------------------
__global__ __launch_bounds__(256, 2) void k2_ffn(
    const float* __restrict__ Vnew, const float* __restrict__ Msum,
    const u16x8* __restrict__ pWf0, const u16x8* __restrict__ pWf1,
    const float* __restrict__ bf0, const float* __restrict__ bf1,
    const float* __restrict__ gmn, const float* __restrict__ bmn,
    const float* __restrict__ gfn, const float* __restrict__ bfn,
    float* __restrict__ out) {
  extern __shared__ char smem[];
  float* V1f = (float*)smem;
  char* A1 = smem + 16384;
  char* hb = smem + 24576;
  const int tid = threadIdx.x;
  const int g0 = blockIdx.x * 32;

  // ---- LN1: V1 = LN(V_new + Msum) ----
  {
    int rr = tid >> 3, sub = tid & 7;
    int rowflat = g0 + rr;
    const float4* vn = (const float4*)(Vnew + rowflat * 128 + sub * 16);
    const float4* ms = (const float4*)(Msum + rowflat * 128 + sub * 16);
    float v[16];
    float s = 0.f, sq = 0.f;
#pragma unroll
    for (int i = 0; i < 4; ++i) {
      float4 a = vn[i], b = ms[i];
      v[4 * i + 0] = a.x + b.x; v[4 * i + 1] = a.y + b.y;
      v[4 * i + 2] = a.z + b.z; v[4 * i + 3] = a.w + b.w;
    }
#pragma unroll
    for (int i = 0; i < 16; ++i) { s += v[i]; sq += v[i] * v[i]; }
    s += __shfl_xor(s, 1);  sq += __shfl_xor(sq, 1);
    s += __shfl_xor(s, 2);  sq += __shfl_xor(sq, 2);
    s += __shfl_xor(s, 4);  sq += __shfl_xor(sq, 4);
    float mean = s * (1.0f / 128.0f);
    float var = sq * (1.0f / 128.0f) - mean * mean;
    float inv = rsqrtf(var + 1e-5f);
#pragma unroll
    for (int i = 0; i < 16; ++i) {
      int c = sub * 16 + i;
      float x = (v[i] - mean) * inv * gmn[c] + bmn[c];
      V1f[rr * 128 + c] = x;
      int byte = rr * 256 + c * 2;
      byte ^= (rr & 7) << 4;
      *(unsigned short*)(A1 + byte) = f2bf(x);
    }
  }
  __syncthreads();

  const int w = tid >> 6, l = tid & 63;
  const int r = l & 15, g = l >> 4;
  const f32x4 zf = {0.f, 0.f, 0.f, 0.f};

  // ---- GEMM1: V1[32x128] @ W_f0[128x512], gelu -> hb ----
  {
    f32x4 acc[2][8];
#pragma unroll
    for (int mt = 0; mt < 2; ++mt)
#pragma unroll
      for (int tt = 0; tt < 8; ++tt) acc[mt][tt] = zf;
#pragma unroll
    for (int s = 0; s < 4; ++s) {
      bf16x8 a[2];
#pragma unroll
      for (int mt = 0; mt < 2; ++mt) a[mt] = ld_afrag(A1, 16 * mt + r, 256, s, g);
#pragma unroll
      for (int tt = 0; tt < 8; ++tt) {
        bf16x8 b = ld_bfrag(pWf0, s, 8 * w + tt, 32, l);
#pragma unroll
        for (int mt = 0; mt < 2; ++mt)
          acc[mt][tt] = __builtin_amdgcn_mfma_f32_16x16x32_bf16(a[mt], b, acc[mt][tt], 0, 0, 0);
      }
    }
#pragma unroll
    for (int mt = 0; mt < 2; ++mt)
#pragma unroll
      for (int tt = 0; tt < 8; ++tt) {
        int col = 128 * w + 16 * tt + r;
        float bias = bf0[col];
#pragma unroll
        for (int j = 0; j < 4; ++j) {
          int row = 16 * mt + 4 * g + j;
          float v = gelu_f(acc[mt][tt][j] + bias);
          int byte = row * 1024 + col * 2;
          byte ^= (row & 7) << 4;
          *(unsigned short*)(hb + byte) = f2bf(v);
        }
      }
  }
  __syncthreads();

  // ---- GEMM2: hb[32x512] @ W_f1[512x128]; residual + bias -> op ----
  {
    f32x4 acc2[2][2];
#pragma unroll
    for (int mt = 0; mt < 2; ++mt)
#pragma unroll
      for (int tt = 0; tt < 2; ++tt) acc2[mt][tt] = zf;
    for (int s = 0; s < 16; ++s) {
      bf16x8 a[2];
#pragma unroll
      for (int mt = 0; mt < 2; ++mt) a[mt] = ld_afrag(hb, 16 * mt + r, 1024, s, g);
#pragma unroll
      for (int tt = 0; tt < 2; ++tt) {
        bf16x8 b = ld_bfrag(pWf1, s, 2 * w + tt, 8, l);
#pragma unroll
        for (int mt = 0; mt < 2; ++mt)
          acc2[mt][tt] = __builtin_amdgcn_mfma_f32_16x16x32_bf16(a[mt], b, acc2[mt][tt], 0, 0, 0);
      }
    }
    __syncthreads();  // all hb reads done; op overlays A1/hb-head
    float* op = (float*)(smem + 16384);
#pragma unroll
    for (int mt = 0; mt < 2; ++mt)
#pragma unroll
      for (int tt = 0; tt < 2; ++tt)
#pragma unroll
        for (int j = 0; j < 4; ++j) {
          int row = 16 * mt + 4 * g + j;
          int col = 32 * w + 16 * tt + r;
          op[row * 128 + col] = V1f[row * 128 + col] + acc2[mt][tt][j] + bf1[col];
        }
  }
  __syncthreads();

  // ---- LN2 + store ----
  {
    const float* op = (const float*)(smem + 16384);
    int rr = tid >> 3, sub = tid & 7;
    float v[16];
    float s = 0.f, sq = 0.f;
#pragma unroll
    for (int i = 0; i < 16; ++i) {
      v[i] = op[rr * 128 + sub * 16 + i];
      s += v[i]; sq += v[i] * v[i];
    }
    s += __shfl_xor(s, 1);  sq += __shfl_xor(sq, 1);
    s += __shfl_xor(s, 2);  sq += __shfl_xor(sq, 2);
    s += __shfl_xor(s, 4);  sq += __shfl_xor(sq, 4);
    float mean = s * (1.0f / 128.0f);
    float var = sq * (1.0f / 128.0f) - mean * mean;
    float inv = rsqrtf(var + 1e-5f);
    int rowflat = g0 + rr;
    float* dst = out + rowflat * 128 + sub * 16;
#pragma unroll
    for (int i = 0; i < 4; ++i) {
      float4 o;
      int c = sub * 16 + 4 * i;
      o.x = (v[4 * i + 0] - mean) * inv * gfn[c + 0] + bfn[c + 0];
      o.y = (v[4 * i + 1] - mean) * inv * gfn[c + 1] + bfn[c + 1];
      o.z = (v[4 * i + 2] - mean) * inv * gfn[c + 2] + bfn[c + 2];
      o.w = (v[4 * i + 3] - mean) * inv * gfn[c + 3] + bfn[c + 3];
      ((float4*)dst)[i] = o;
    }
  }
}

extern "C" void kernel_launch(void* const* d_in, const int* in_sizes, int n_in,
                              void* d_out, int out_size, void* d_ws, size_t ws_size,
                              hipStream_t stream) {
  const float* Vnew = (const float*)d_in[0];
  const float* Vold = (const float*)d_in[1];
  const float* E    = (const float*)d_in[2];
  const float* S    = (const float*)d_in[3];
  const int* Kidx   = (const int*)d_in[4];
  const void* emask = d_in[5];
  const void* amask = d_in[6];
  const float* Wm0 = (const float*)d_in[7];  const float* bm0 = (const float*)d_in[8];
  const float* Wm1 = (const float*)d_in[9];  const float* bm1 = (const float*)d_in[10];
  const float* Wm2 = (const float*)d_in[11]; const float* bm2 = (const float*)d_in[12];
  const float* gmn = (const float*)d_in[13]; const float* bmn = (const float*)d_in[14];
  const float* Wf0 = (const float*)d_in[15]; const float* bf0 = (const float*)d_in[16];
  const float* Wf1 = (const float*)d_in[17]; const float* bf1 = (const float*)d_in[18];
  const float* gfn = (const float*)d_in[19]; const float* bfn = (const float*)d_in[20];

  unsigned short* pack = (unsigned short*)d_ws;           // 229376 bf16 = 458752 B
  float* Msum = (float*)((char*)d_ws + 458752);           // 4 MiB
  int* modeflag = (int*)((char*)d_ws + 458752 + 4194304); // 4 B
  float* out = (float*)d_out;

  k0_pack<<<896, 256, 0, stream>>>(Wm0, Wm1, Wm2, Wf0, Wf1, pack);
  kd_detect<<<1, 256, 0, stream>>>((const unsigned char*)emask, modeflag);
  k1_edge_mlp<<<4096, 256, 50432, stream>>>(
      Vnew, Vold, E, S, Kidx, emask, amask, Wm0,
      (const u16x8*)pack, (const u16x8*)(pack + 65536), (const u16x8*)(pack + 81920),
      bm0, bm1, bm2, modeflag, Msum);
  k2_ffn<<<256, 256, 57344, stream>>>(
      Vnew, Msum,
      (const u16x8*)(pack + 98304), (const u16x8*)(pack + 163840),
      bf0, bf1, gmn, bmn, gfn, bfn, out);
}

// Round 4
// 360.536 us; speedup vs baseline: 1.1938x; 1.1938x over previous
//
#include <hip/hip_runtime.h>
#include <math.h>

#define NN 2048
#define KN 30

typedef __bf16 bf16x8 __attribute__((ext_vector_type(8)));
typedef float f32x4 __attribute__((ext_vector_type(4)));
typedef unsigned short u16x8 __attribute__((ext_vector_type(8)));
typedef unsigned short u16x4 __attribute__((ext_vector_type(4)));

__device__ __forceinline__ unsigned short f2bf(float f) {
  unsigned u = __builtin_bit_cast(unsigned, f);
  u += 0x7FFFu + ((u >> 16) & 1u);
  return (unsigned short)(u >> 16);
}

// exact GELU (matches jax approximate=False); round-2-verified numerics
__device__ __forceinline__ float gelu_f(float x) {
  return 0.5f * x * (1.0f + erff(x * 0.70710678118654752f));
}

// mask read per mode: 1=uint8, 2=float32, 0=int32
__device__ __forceinline__ bool rdmask(const void* p, int i, int mode) {
  if (mode == 1) return ((const unsigned char*)p)[i] != 0;
  if (mode == 2) return ((const float*)p)[i] != 0.0f;
  return ((const int*)p)[i] != 0;
}

// A-fragment: lane (l&15) = row in 16-row tile; 8 bf16 along K at 32*s+8*(l>>4).
// LDS rows XOR-swizzled by ((row&7)<<4).
__device__ __forceinline__ bf16x8 ld_afrag(const char* base, int row, int rowstride, int s, int g) {
  int byte = row * rowstride + s * 64 + g * 16;
  byte ^= (row & 7) << 4;
  u16x8 u = *(const u16x8*)(base + byte);
  return __builtin_bit_cast(bf16x8, u);
}

__device__ __forceinline__ bf16x8 ld_bfrag(const u16x8* __restrict__ pw, int s, int t, int NT, int lane) {
  u16x8 u = pw[(s * NT + t) * 64 + lane];
  return __builtin_bit_cast(bf16x8, u);
}

// ---------------------------------------------------------------------------
// K0: pack 5 weight matrices f32 -> bf16, fragment-major.
// p = ((s*NT + t)*64 + l)*8 + j  holds  W[32*s + 8*(l>>4) + j][16*t + (l&15)]
// bf16 elem ranges: m0 [0,65536) m1 [65536,81920) m2 [81920,98304)
//                   f0 [98304,163840) f1 [163840,229376)
// ---------------------------------------------------------------------------
__global__ void k0_pack(const float* __restrict__ Wm0, const float* __restrict__ Wm1,
                        const float* __restrict__ Wm2, const float* __restrict__ Wf0,
                        const float* __restrict__ Wf1, unsigned short* __restrict__ dst) {
  int i = blockIdx.x * 256 + threadIdx.x;
  if (i >= 229376) return;
  const float* W;
  int base, Nc;
  if (i < 65536)       { W = Wm0; base = 0;      Nc = 128; }
  else if (i < 81920)  { W = Wm1; base = 65536;  Nc = 128; }
  else if (i < 98304)  { W = Wm2; base = 81920;  Nc = 128; }
  else if (i < 163840) { W = Wf0; base = 98304;  Nc = 512; }
  else                 { W = Wf1; base = 163840; Nc = 128; }
  int NT = Nc >> 4;
  int p = i - base;
  int j = p & 7;
  int l = (p >> 3) & 63;
  int rest = p >> 9;
  int t = rest % NT;
  int s = rest / NT;
  int kk = 32 * s + 8 * (l >> 4) + j;
  int c = 16 * t + (l & 15);
  dst[i] = f2bf(W[kk * Nc + c]);
}

// ---------------------------------------------------------------------------
// K1: per-WG = 2 nodes (60 edges + 4 pad rows). A-tile [64][384] bf16
// (Vj|E|Es), coalesced flat staging via per-row pointer table; inline f32
// Vi matvec vb = Vi @ Wm0[0:128] (round-2 numerics).
// LDS: stage [0,49152); h0 overlays [0,16384); h1 [16384,32768);
//      vb f32[256] @49152; em f32[64] @50176; ptrs u64[192] @50432. = 51968 B
// ---------------------------------------------------------------------------
__global__ __launch_bounds__(256, 3) void k1_edge_mlp(
    const float* __restrict__ Vnew, const float* __restrict__ Vold,
    const float* __restrict__ E, const float* __restrict__ S,
    const int* __restrict__ Kidx, const void* __restrict__ emask,
    const void* __restrict__ amask,
    const float* __restrict__ Wm0f,
    const u16x8* __restrict__ pWm0, const u16x8* __restrict__ pWm1,
    const u16x8* __restrict__ pWm2,
    const float* __restrict__ bm0, const float* __restrict__ bm1,
    const float* __restrict__ bm2,
    float* __restrict__ Msum) {
  extern __shared__ char smem[];
  float* vb = (float*)(smem + 49152);                              // [2][128]
  float* em_lds = (float*)(smem + 50176);                          // [64]
  unsigned long long* ptrs = (unsigned long long*)(smem + 50432);  // [64][3]
  const int tid = threadIdx.x;
  const int p = blockIdx.x;
  const int z = (2 * p) / NN;
  const int n0 = (2 * p) % NN;

  // ---- phase A: wave0 = mask-mode detect + per-row pointers + em ----
  if (tid < 64) {
    int boff = (z * NN + n0) * KN;                 // divisible by 4
    if (boff > 245760 - 256) boff = 245760 - 256;
    unsigned dv = *(const unsigned*)((const char*)emask + boff + 4 * tid);
    unsigned long long b1 = __ballot(dv == 1u);
    unsigned long long bf = __ballot(dv == 0x3F800000u);
    int mode = (__popcll(bf) > 16) ? 2 : ((__popcll(b1) > 16) ? 0 : 1);
    int row = tid;
    const float *pVj = nullptr, *pE = nullptr, *pEs = nullptr;
    float em = 0.f;
    if (row < 60) {
      int ln = row >= 30;
      int n = n0 + ln;
      int k = row - 30 * ln;
      int eidx = (z * NN + n) * KN + k;
      int kidx = Kidx[eidx];
      bool am = rdmask(amask, eidx, mode);
      em = rdmask(emask, eidx, mode) ? 1.0f : 0.0f;
      pVj = (am ? Vnew : Vold) + (z * NN + kidx) * 128;
      pE = E + (long)eidx * 128;
      pEs = am ? (S + (z * NN + kidx) * 128) : nullptr;
    }
    em_lds[row] = em;
    ptrs[row * 3 + 0] = (unsigned long long)pVj;
    ptrs[row * 3 + 1] = (unsigned long long)pE;
    ptrs[row * 3 + 2] = (unsigned long long)pEs;
  }

  // ---- vb[node][col] = Vnew[node] . Wm0[0:128][col]  (f32, 4-way ILP) ----
  {
    int nd = tid >> 7, col = tid & 127;
    const float* vi = Vnew + (z * NN + n0 + nd) * 128;
    float a0 = 0.f, a1 = 0.f, a2 = 0.f, a3 = 0.f;
#pragma unroll 8
    for (int k = 0; k < 128; k += 4) {
      a0 = fmaf(vi[k + 0], Wm0f[(k + 0) * 128 + col], a0);
      a1 = fmaf(vi[k + 1], Wm0f[(k + 1) * 128 + col], a1);
      a2 = fmaf(vi[k + 2], Wm0f[(k + 2) * 128 + col], a2);
      a3 = fmaf(vi[k + 3], Wm0f[(k + 3) * 128 + col], a3);
    }
    vb[nd * 128 + col] = (a0 + a1) + (a2 + a3);
  }
  __syncthreads();  // ptrs/em ready (vb written before next sync; read after)

  // ---- flat coalesced staging: 3072 x 32B units, 12 iters ----
#pragma unroll 4
  for (int i = 0; i < 12; ++i) {
    int pf = i * 256 + tid;            // [0,3072)
    int t = pf >> 4;                   // [0,192)
    int row = (t * 2731) >> 13;        // t/3 exact for t<4096
    int rem = pf - row * 48;
    int seg = rem >> 4;                // 0=Vj 1=E 2=Es
    int idx2 = rem & 15;               // 32B unit within 512B segment
    const float4* sp = (const float4*)ptrs[row * 3 + seg];
    float4 v0 = sp ? sp[2 * idx2] : make_float4(0.f, 0.f, 0.f, 0.f);
    float4 v1 = sp ? sp[2 * idx2 + 1] : make_float4(0.f, 0.f, 0.f, 0.f);
    u16x8 h;
    h[0] = f2bf(v0.x); h[1] = f2bf(v0.y); h[2] = f2bf(v0.z); h[3] = f2bf(v0.w);
    h[4] = f2bf(v1.x); h[5] = f2bf(v1.y); h[6] = f2bf(v1.z); h[7] = f2bf(v1.w);
    int byte = row * 768 + ((seg * 256 + idx2 * 16) ^ ((row & 7) << 4));
    *(u16x8*)(smem + byte) = h;
  }
  __syncthreads();

  const int w = tid >> 6, l = tid & 63;
  const int r = l & 15, g = l >> 4;
  float bb0[2], bb1[2], bb2[2];
#pragma unroll
  for (int tt = 0; tt < 2; ++tt) {
    int col = 32 * w + 16 * tt + r;
    bb0[tt] = bm0[col]; bb1[tt] = bm1[col]; bb2[tt] = bm2[col];
  }
  const f32x4 zf = {0.f, 0.f, 0.f, 0.f};

  // ---- layer 0: [64x384] @ Wm0[128:512][128]  (B s-offset +4) ----
  f32x4 acc[4][2];
#pragma unroll
  for (int mt = 0; mt < 4; ++mt)
#pragma unroll
    for (int tt = 0; tt < 2; ++tt) acc[mt][tt] = zf;
  for (int s = 0; s < 12; ++s) {
    bf16x8 a[4];
#pragma unroll
    for (int mt = 0; mt < 4; ++mt) a[mt] = ld_afrag(smem, 16 * mt + r, 768, s, g);
#pragma unroll
    for (int tt = 0; tt < 2; ++tt) {
      bf16x8 b = ld_bfrag(pWm0, s + 4, 2 * w + tt, 8, l);
#pragma unroll
      for (int mt = 0; mt < 4; ++mt)
        acc[mt][tt] = __builtin_amdgcn_mfma_f32_16x16x32_bf16(a[mt], b, acc[mt][tt], 0, 0, 0);
    }
  }
  __syncthreads();  // all waves done reading A tile
  char* h0 = smem;  // [64][128] bf16, swizzled, rowstride 256
#pragma unroll
  for (int mt = 0; mt < 4; ++mt)
#pragma unroll
    for (int tt = 0; tt < 2; ++tt)
#pragma unroll
      for (int j = 0; j < 4; ++j) {
        int row = 16 * mt + 4 * g + j;
        int col = 32 * w + 16 * tt + r;
        float v = 0.f;
        if (row < 60)
          v = gelu_f(acc[mt][tt][j] + vb[(row >= 30) * 128 + col] + bb0[tt]);
        int byte = row * 256 + col * 2;
        byte ^= (row & 7) << 4;
        *(unsigned short*)(h0 + byte) = f2bf(v);
      }
  __syncthreads();

  // ---- layer 1 ----
  char* h1 = smem + 16384;
  {
    f32x4 acc1[4][2];
#pragma unroll
    for (int mt = 0; mt < 4; ++mt)
#pragma unroll
      for (int tt = 0; tt < 2; ++tt) acc1[mt][tt] = zf;
#pragma unroll
    for (int s = 0; s < 4; ++s) {
      bf16x8 a[4];
#pragma unroll
      for (int mt = 0; mt < 4; ++mt) a[mt] = ld_afrag(h0, 16 * mt + r, 256, s, g);
#pragma unroll
      for (int tt = 0; tt < 2; ++tt) {
        bf16x8 b = ld_bfrag(pWm1, s, 2 * w + tt, 8, l);
#pragma unroll
        for (int mt = 0; mt < 4; ++mt)
          acc1[mt][tt] = __builtin_amdgcn_mfma_f32_16x16x32_bf16(a[mt], b, acc1[mt][tt], 0, 0, 0);
      }
    }
#pragma unroll
    for (int mt = 0; mt < 4; ++mt)
#pragma unroll
      for (int tt = 0; tt < 2; ++tt)
#pragma unroll
        for (int j = 0; j < 4; ++j) {
          int row = 16 * mt + 4 * g + j;
          int col = 32 * w + 16 * tt + r;
          float v = gelu_f(acc1[mt][tt][j] + bb1[tt]);
          int byte = row * 256 + col * 2;
          byte ^= (row & 7) << 4;
          *(unsigned short*)(h1 + byte) = f2bf(v);
        }
  }
  __syncthreads();

  // ---- layer 2 + fragment-level masked node-sum -> Msum ----
  {
    f32x4 acc2[4][2];
#pragma unroll
    for (int mt = 0; mt < 4; ++mt)
#pragma unroll
      for (int tt = 0; tt < 2; ++tt) acc2[mt][tt] = zf;
#pragma unroll
    for (int s = 0; s < 4; ++s) {
      bf16x8 a[4];
#pragma unroll
      for (int mt = 0; mt < 4; ++mt) a[mt] = ld_afrag(h1, 16 * mt + r, 256, s, g);
#pragma unroll
      for (int tt = 0; tt < 2; ++tt) {
        bf16x8 b = ld_bfrag(pWm2, s, 2 * w + tt, 8, l);
#pragma unroll
        for (int mt = 0; mt < 4; ++mt)
          acc2[mt][tt] = __builtin_amdgcn_mfma_f32_16x16x32_bf16(a[mt], b, acc2[mt][tt], 0, 0, 0);
      }
    }
    float s0[2] = {0.f, 0.f}, s1[2] = {0.f, 0.f};
#pragma unroll
    for (int mt = 0; mt < 4; ++mt)
#pragma unroll
      for (int tt = 0; tt < 2; ++tt)
#pragma unroll
        for (int j = 0; j < 4; ++j) {
          int row = 16 * mt + 4 * g + j;
          float v = (acc2[mt][tt][j] + bb2[tt]) * em_lds[row];  // pads: em=0
          if (row < 30) s0[tt] += v; else s1[tt] += v;
        }
#pragma unroll
    for (int tt = 0; tt < 2; ++tt) {
      s0[tt] += __shfl_xor(s0[tt], 16); s0[tt] += __shfl_xor(s0[tt], 32);
      s1[tt] += __shfl_xor(s1[tt], 16); s1[tt] += __shfl_xor(s1[tt], 32);
    }
    if (g == 0) {
#pragma unroll
      for (int tt = 0; tt < 2; ++tt)
        Msum[(z * NN + n0) * 128 + 32 * w + 16 * tt + r] = s0[tt];
    } else if (g == 1) {
#pragma unroll
      for (int tt = 0; tt < 2; ++tt)
        Msum[(z * NN + n0 + 1) * 128 + 32 * w + 16 * tt + r] = s1[tt];
    }
  }
}

// ---------------------------------------------------------------------------
// K2: 16 nodes/WG (grid 512). LN1 -> FFN (MFMA) -> LN2 -> out.
// LDS: V1f f32 [16][128] @0 (8K); A1 bf16 @8192 (4K, swz);
//      hb bf16 [16][512] @12288 (16K, swz); op f32 @8192 (8K, reuse). = 28672 B
// ---------------------------------------------------------------------------
__global__ __launch_bounds__(256, 2) void k2_ffn(
    const float* __restrict__ Vnew, const float* __restrict__ Msum,
    const u16x8* __restrict__ pWf0, const u16x8* __restrict__ pWf1,
    const float* __restrict__ bf0, const float* __restrict__ bf1,
    const float* __restrict__ gmn, const float* __restrict__ bmn,
    const float* __restrict__ gfn, const float* __restrict__ bfn,
    float* __restrict__ out) {
  extern __shared__ char smem[];
  float* V1f = (float*)smem;
  char* A1 = smem + 8192;
  char* hb = smem + 12288;
  const int tid = threadIdx.x;
  const int g0 = blockIdx.x * 16;

  // ---- LN1: V1 = LN(V_new + Msum); 16 lanes/row x 8 cols ----
  {
    int rr = tid >> 4, sub = tid & 15;
    int rowflat = g0 + rr;
    const float4* vn = (const float4*)(Vnew + rowflat * 128 + sub * 8);
    const float4* ms = (const float4*)(Msum + rowflat * 128 + sub * 8);
    float4 a0 = vn[0], a1 = vn[1], m0 = ms[0], m1 = ms[1];
    float v[8] = {a0.x + m0.x, a0.y + m0.y, a0.z + m0.z, a0.w + m0.w,
                  a1.x + m1.x, a1.y + m1.y, a1.z + m1.z, a1.w + m1.w};
    float s = 0.f, sq = 0.f;
#pragma unroll
    for (int i = 0; i < 8; ++i) { s += v[i]; sq += v[i] * v[i]; }
    s += __shfl_xor(s, 1);  sq += __shfl_xor(sq, 1);
    s += __shfl_xor(s, 2);  sq += __shfl_xor(sq, 2);
    s += __shfl_xor(s, 4);  sq += __shfl_xor(sq, 4);
    s += __shfl_xor(s, 8);  sq += __shfl_xor(sq, 8);
    float mean = s * (1.0f / 128.0f);
    float var = sq * (1.0f / 128.0f) - mean * mean;
    float inv = rsqrtf(var + 1e-5f);
    u16x4 h0v, h1v;
#pragma unroll
    for (int i = 0; i < 8; ++i) {
      int c = sub * 8 + i;
      float x = (v[i] - mean) * inv * gmn[c] + bmn[c];
      V1f[rr * 128 + c] = x;
      if (i < 4) h0v[i] = f2bf(x); else h1v[i - 4] = f2bf(x);
    }
    int byte = rr * 256 + ((sub * 16) ^ ((rr & 7) << 4));
    *(u16x4*)(A1 + byte) = h0v;
    *(u16x4*)(A1 + byte + 8) = h1v;
  }
  __syncthreads();

  const int w = tid >> 6, l = tid & 63;
  const int r = l & 15, g = l >> 4;
  const f32x4 zf = {0.f, 0.f, 0.f, 0.f};

  // ---- GEMM1: V1[16x128] @ W_f0[128x512], gelu -> hb ----
  {
    f32x4 acc[8];
#pragma unroll
    for (int tt = 0; tt < 8; ++tt) acc[tt] = zf;
#pragma unroll
    for (int s = 0; s < 4; ++s) {
      bf16x8 a = ld_afrag(A1, r, 256, s, g);
#pragma unroll
      for (int tt = 0; tt < 8; ++tt) {
        bf16x8 b = ld_bfrag(pWf0, s, 8 * w + tt, 32, l);
        acc[tt] = __builtin_amdgcn_mfma_f32_16x16x32_bf16(a, b, acc[tt], 0, 0, 0);
      }
    }
#pragma unroll
    for (int tt = 0; tt < 8; ++tt) {
      int col = 128 * w + 16 * tt + r;
      float bias = bf0[col];
#pragma unroll
      for (int j = 0; j < 4; ++j) {
        int row = 4 * g + j;
        float v = gelu_f(acc[tt][j] + bias);
        int byte = row * 1024 + col * 2;
        byte ^= (row & 7) << 4;
        *(unsigned short*)(hb + byte) = f2bf(v);
      }
    }
  }
  __syncthreads();

  // ---- GEMM2: hb[16x512] @ W_f1[512x128]; +residual +bias -> op ----
  {
    f32x4 acc2[2];
#pragma unroll
    for (int tt = 0; tt < 2; ++tt) acc2[tt] = zf;
    for (int s = 0; s < 16; ++s) {
      bf16x8 a = ld_afrag(hb, r, 1024, s, g);
#pragma unroll
      for (int tt = 0; tt < 2; ++tt) {
        bf16x8 b = ld_bfrag(pWf1, s, 2 * w + tt, 8, l);
        acc2[tt] = __builtin_amdgcn_mfma_f32_16x16x32_bf16(a, b, acc2[tt], 0, 0, 0);
      }
    }
    __syncthreads();  // all hb reads done; op overlays A1 + hb head
    float* op = (float*)(smem + 8192);
#pragma unroll
    for (int tt = 0; tt < 2; ++tt)
#pragma unroll
      for (int j = 0; j < 4; ++j) {
        int row = 4 * g + j;
        int col = 32 * w + 16 * tt + r;
        op[row * 128 + col] = V1f[row * 128 + col] + acc2[tt][j] + bf1[col];
      }
  }
  __syncthreads();

  // ---- LN2 + store ----
  {
    const float* op = (const float*)(smem + 8192);
    int rr = tid >> 4, sub = tid & 15;
    float v[8];
    float s = 0.f, sq = 0.f;
#pragma unroll
    for (int i = 0; i < 8; ++i) {
      v[i] = op[rr * 128 + sub * 8 + i];
      s += v[i]; sq += v[i] * v[i];
    }
    s += __shfl_xor(s, 1);  sq += __shfl_xor(sq, 1);
    s += __shfl_xor(s, 2);  sq += __shfl_xor(sq, 2);
    s += __shfl_xor(s, 4);  sq += __shfl_xor(sq, 4);
    s += __shfl_xor(s, 8);  sq += __shfl_xor(sq, 8);
    float mean = s * (1.0f / 128.0f);
    float var = sq * (1.0f / 128.0f) - mean * mean;
    float inv = rsqrtf(var + 1e-5f);
    int rowflat = g0 + rr;
    float* dst = out + rowflat * 128 + sub * 8;
    float4 o0, o1;
    int c = sub * 8;
    o0.x = (v[0] - mean) * inv * gfn[c + 0] + bfn[c + 0];
    o0.y = (v[1] - mean) * inv * gfn[c + 1] + bfn[c + 1];
    o0.z = (v[2] - mean) * inv * gfn[c + 2] + bfn[c + 2];
    o0.w = (v[3] - mean) * inv * gfn[c + 3] + bfn[c + 3];
    o1.x = (v[4] - mean) * inv * gfn[c + 4] + bfn[c + 4];
    o1.y = (v[5] - mean) * inv * gfn[c + 5] + bfn[c + 5];
    o1.z = (v[6] - mean) * inv * gfn[c + 6] + bfn[c + 6];
    o1.w = (v[7] - mean) * inv * gfn[c + 7] + bfn[c + 7];
    ((float4*)dst)[0] = o0;
    ((float4*)dst)[1] = o1;
  }
}

extern "C" void kernel_launch(void* const* d_in, const int* in_sizes, int n_in,
                              void* d_out, int out_size, void* d_ws, size_t ws_size,
                              hipStream_t stream) {
  const float* Vnew = (const float*)d_in[0];
  const float* Vold = (const float*)d_in[1];
  const float* E    = (const float*)d_in[2];
  const float* S    = (const float*)d_in[3];
  const int* Kidx   = (const int*)d_in[4];
  const void* emask = d_in[5];
  const void* amask = d_in[6];
  const float* Wm0 = (const float*)d_in[7];  const float* bm0 = (const float*)d_in[8];
  const float* Wm1 = (const float*)d_in[9];  const float* bm1 = (const float*)d_in[10];
  const float* Wm2 = (const float*)d_in[11]; const float* bm2 = (const float*)d_in[12];
  const float* gmn = (const float*)d_in[13]; const float* bmn = (const float*)d_in[14];
  const float* Wf0 = (const float*)d_in[15]; const float* bf0 = (const float*)d_in[16];
  const float* Wf1 = (const float*)d_in[17]; const float* bf1 = (const float*)d_in[18];
  const float* gfn = (const float*)d_in[19]; const float* bfn = (const float*)d_in[20];

  unsigned short* pack = (unsigned short*)d_ws;  // 458752 B
  float* Msum = (float*)((char*)d_ws + 458752);  // 4 MiB
  float* out = (float*)d_out;

  k0_pack<<<896, 256, 0, stream>>>(Wm0, Wm1, Wm2, Wf0, Wf1, pack);
  k1_edge_mlp<<<4096, 256, 51968, stream>>>(
      Vnew, Vold, E, S, Kidx, emask, amask, Wm0,
      (const u16x8*)pack, (const u16x8*)(pack + 65536), (const u16x8*)(pack + 81920),
      bm0, bm1, bm2, Msum);
  k2_ffn<<<512, 256, 28672, stream>>>(
      Vnew, Msum,
      (const u16x8*)(pack + 98304), (const u16x8*)(pack + 163840),
      bf0, bf1, gmn, bmn, gfn, bfn, out);
}

// Round 8
// 336.180 us; speedup vs baseline: 1.2803x; 1.0724x over previous
//
#include <hip/hip_runtime.h>
#include <math.h>

#define NN 2048
#define KN 30

typedef __bf16 bf16x8 __attribute__((ext_vector_type(8)));
typedef float f32x4 __attribute__((ext_vector_type(4)));
typedef unsigned short u16x8 __attribute__((ext_vector_type(8)));
typedef unsigned short u16x4 __attribute__((ext_vector_type(4)));

// bit-math RNE f32->bf16 — the round-2/4-PROVEN conversion. Do NOT replace
// with (__bf16) cast: round-7 A/B showed the cast inflates absmax 0.078->0.125
// (non-RNE lowering).
__device__ __forceinline__ unsigned short f2bf(float f) {
  unsigned u = __builtin_bit_cast(unsigned, f);
  u += 0x7FFFu + ((u >> 16) & 1u);
  return (unsigned short)(u >> 16);
}

// exact GELU (matches jax approximate=False); round-2/4-verified numerics
__device__ __forceinline__ float gelu_f(float x) {
  return 0.5f * x * (1.0f + erff(x * 0.70710678118654752f));
}

// mask read per mode: 1=uint8, 2=float32, 0=int32
__device__ __forceinline__ bool rdmask(const void* p, int i, int mode) {
  if (mode == 1) return ((const unsigned char*)p)[i] != 0;
  if (mode == 2) return ((const float*)p)[i] != 0.0f;
  return ((const int*)p)[i] != 0;
}

// A-fragment: lane (l&15) = row in 16-row tile; 8 bf16 along K at 32*s+8*(l>>4).
// LDS rows XOR-swizzled by ((row&7)<<4).
__device__ __forceinline__ bf16x8 ld_afrag(const char* base, int row, int rowstride, int s, int g) {
  int byte = row * rowstride + s * 64 + g * 16;
  byte ^= (row & 7) << 4;
  u16x8 u = *(const u16x8*)(base + byte);
  return __builtin_bit_cast(bf16x8, u);
}

__device__ __forceinline__ bf16x8 ld_bfrag(const u16x8* __restrict__ pw, int s, int t, int NT, int lane) {
  u16x8 u = pw[(s * NT + t) * 64 + lane];
  return __builtin_bit_cast(bf16x8, u);
}

// ---------------------------------------------------------------------------
// K0: pack 5 weight matrices f32 -> bf16, fragment-major.
// p = ((s*NT + t)*64 + l)*8 + j  holds  W[32*s + 8*(l>>4) + j][16*t + (l&15)]
// bf16 elem ranges: m0 [0,65536) m1 [65536,81920) m2 [81920,98304)
//                   f0 [98304,163840) f1 [163840,229376)
// ---------------------------------------------------------------------------
__global__ void k0_pack(const float* __restrict__ Wm0, const float* __restrict__ Wm1,
                        const float* __restrict__ Wm2, const float* __restrict__ Wf0,
                        const float* __restrict__ Wf1, unsigned short* __restrict__ dst) {
  int i = blockIdx.x * 256 + threadIdx.x;
  if (i >= 229376) return;
  const float* W;
  int base, Nc;
  if (i < 65536)       { W = Wm0; base = 0;      Nc = 128; }
  else if (i < 81920)  { W = Wm1; base = 65536;  Nc = 128; }
  else if (i < 98304)  { W = Wm2; base = 81920;  Nc = 128; }
  else if (i < 163840) { W = Wf0; base = 98304;  Nc = 512; }
  else                 { W = Wf1; base = 163840; Nc = 128; }
  int NT = Nc >> 4;
  int p = i - base;
  int j = p & 7;
  int l = (p >> 3) & 63;
  int rest = p >> 9;
  int t = rest % NT;
  int s = rest / NT;
  int kk = 32 * s + 8 * (l >> 4) + j;
  int c = 16 * t + (l & 15);
  dst[i] = f2bf(W[kk * Nc + c]);
}

// ---------------------------------------------------------------------------
// KVB: VB[row][col] = Vnew[row][:] . Wm0[0:128][col]  (f32 math, f32 store).
// grid 512, 16 rows/block, 8-row ILP per thread.
// ---------------------------------------------------------------------------
__global__ __launch_bounds__(256) void kvb(const float* __restrict__ Vnew,
                                           const float* __restrict__ Wm0f,
                                           float* __restrict__ VB) {
  int col = threadIdx.x & 127, half = threadIdx.x >> 7;
  int base = blockIdx.x * 16 + half * 8;
  float acc[8] = {0.f, 0.f, 0.f, 0.f, 0.f, 0.f, 0.f, 0.f};
#pragma unroll 4
  for (int k = 0; k < 128; ++k) {
    float wv = Wm0f[k * 128 + col];
#pragma unroll
    for (int r = 0; r < 8; ++r)
      acc[r] = fmaf(Vnew[(base + r) * 128 + k], wv, acc[r]);
  }
#pragma unroll
  for (int r = 0; r < 8; ++r) VB[(base + r) * 128 + col] = acc[r];
}

// ---------------------------------------------------------------------------
// K1: per-WG = 1 node (30 edges + 2 pad rows, M=32). A-tile [32][384] bf16
// (Vj|E|Es), coalesced flat staging via per-row pointer table; Vi contribution
// from f32 VB (kvb) or inline f32 matvec fallback.
// Mask-mode detect reads a FIXED aligned window at emask+0 (mode is global;
// round-5's per-block window hit misaligned-dword faults on odd nodes).
// LDS: stage [0,24576); h0 overlays [0,8192); h1 [8192,16384);
//      vb f32[128] @24576; em f32[32] @25088; ptrs u64[96] @25216. = 25984 B
// 6 blocks/CU (24 waves/CU) for latency hiding.
// ---------------------------------------------------------------------------
template <bool UV>
__global__ __launch_bounds__(256, 6) void k1_edge_mlp(
    const float* __restrict__ Vnew, const float* __restrict__ Vold,
    const float* __restrict__ E, const float* __restrict__ S,
    const int* __restrict__ Kidx, const void* __restrict__ emask,
    const void* __restrict__ amask,
    const float* __restrict__ VB, const float* __restrict__ Wm0f,
    const u16x8* __restrict__ pWm0, const u16x8* __restrict__ pWm1,
    const u16x8* __restrict__ pWm2,
    const float* __restrict__ bm0, const float* __restrict__ bm1,
    const float* __restrict__ bm2,
    float* __restrict__ Msum) {
  extern __shared__ char smem[];
  float* vb = (float*)(smem + 24576);                              // [128]
  float* em_lds = (float*)(smem + 25088);                          // [32]
  unsigned long long* ptrs = (unsigned long long*)(smem + 25216);  // [32][3]
  const int tid = threadIdx.x;
  const int p = blockIdx.x;
  const int z = p >> 11;
  const int n = p & (NN - 1);

  // ---- phase A: wave0 = mask-mode detect (fixed window @0) + pointers ----
  if (tid < 64) {
    unsigned dv = *(const unsigned*)((const char*)emask + 4 * tid);
    unsigned long long b1 = __ballot(dv == 1u);
    unsigned long long bfp = __ballot(dv == 0x3F800000u);
    int mode = (__popcll(bfp) > 16) ? 2 : ((__popcll(b1) > 16) ? 0 : 1);
    int row = tid;
    if (row < 32) {
      const float *pVj = nullptr, *pE = nullptr, *pEs = nullptr;
      float em = 0.f;
      if (row < 30) {
        int eidx = (z * NN + n) * KN + row;
        int kidx = Kidx[eidx];
        bool am = rdmask(amask, eidx, mode);
        em = rdmask(emask, eidx, mode) ? 1.0f : 0.0f;
        pVj = (am ? Vnew : Vold) + (z * NN + kidx) * 128;
        pE = E + (long)eidx * 128;
        pEs = am ? (S + (z * NN + kidx) * 128) : nullptr;
      }
      em_lds[row] = em;
      ptrs[row * 3 + 0] = (unsigned long long)pVj;
      ptrs[row * 3 + 1] = (unsigned long long)pE;
      ptrs[row * 3 + 2] = (unsigned long long)pEs;
    }
  }
  if (UV) {
    if (tid >= 64 && tid < 192) vb[tid - 64] = VB[(z * NN + n) * 128 + (tid - 64)];
  } else if (tid >= 128) {  // fallback: inline f32 matvec on free lanes
    int col = tid - 128;
    const float* vi = Vnew + (z * NN + n) * 128;
    float a0 = 0.f, a1 = 0.f, a2 = 0.f, a3 = 0.f;
#pragma unroll 8
    for (int k = 0; k < 128; k += 4) {
      a0 = fmaf(vi[k + 0], Wm0f[(k + 0) * 128 + col], a0);
      a1 = fmaf(vi[k + 1], Wm0f[(k + 1) * 128 + col], a1);
      a2 = fmaf(vi[k + 2], Wm0f[(k + 2) * 128 + col], a2);
      a3 = fmaf(vi[k + 3], Wm0f[(k + 3) * 128 + col], a3);
    }
    vb[col] = (a0 + a1) + (a2 + a3);
  }
  __syncthreads();

  // ---- flat coalesced staging: 1536 x 32B units, 6 iters ----
#pragma unroll
  for (int i = 0; i < 6; ++i) {
    int pf = i * 256 + tid;            // [0,1536)
    int t = pf >> 4;                   // [0,96)
    int row = (t * 2731) >> 13;        // t/3 exact for t<4096
    int rem = pf - row * 48;
    int seg = rem >> 4;                // 0=Vj 1=E 2=Es
    int idx2 = rem & 15;               // 32B unit within 512B segment
    const float4* sp = (const float4*)ptrs[row * 3 + seg];
    float4 v0 = sp ? sp[2 * idx2] : make_float4(0.f, 0.f, 0.f, 0.f);
    float4 v1 = sp ? sp[2 * idx2 + 1] : make_float4(0.f, 0.f, 0.f, 0.f);
    u16x8 h;
    h[0] = f2bf(v0.x); h[1] = f2bf(v0.y); h[2] = f2bf(v0.z); h[3] = f2bf(v0.w);
    h[4] = f2bf(v1.x); h[5] = f2bf(v1.y); h[6] = f2bf(v1.z); h[7] = f2bf(v1.w);
    int byte = row * 768 + ((seg * 256 + idx2 * 16) ^ ((row & 7) << 4));
    *(u16x8*)(smem + byte) = h;
  }
  __syncthreads();

  const int w = tid >> 6, l = tid & 63;
  const int r = l & 15, g = l >> 4;
  float bb0[2], bb1[2], bb2[2];
#pragma unroll
  for (int tt = 0; tt < 2; ++tt) {
    int col = 32 * w + 16 * tt + r;
    bb0[tt] = bm0[col]; bb1[tt] = bm1[col]; bb2[tt] = bm2[col];
  }
  const f32x4 zf = {0.f, 0.f, 0.f, 0.f};

  // ---- layer 0: [32x384] @ Wm0[128:512][128]  (B s-offset +4) ----
  f32x4 acc[2][2];
#pragma unroll
  for (int mt = 0; mt < 2; ++mt)
#pragma unroll
    for (int tt = 0; tt < 2; ++tt) acc[mt][tt] = zf;
  for (int s = 0; s < 12; ++s) {
    bf16x8 a[2];
#pragma unroll
    for (int mt = 0; mt < 2; ++mt) a[mt] = ld_afrag(smem, 16 * mt + r, 768, s, g);
#pragma unroll
    for (int tt = 0; tt < 2; ++tt) {
      bf16x8 b = ld_bfrag(pWm0, s + 4, 2 * w + tt, 8, l);
#pragma unroll
      for (int mt = 0; mt < 2; ++mt)
        acc[mt][tt] = __builtin_amdgcn_mfma_f32_16x16x32_bf16(a[mt], b, acc[mt][tt], 0, 0, 0);
    }
  }
  __syncthreads();  // all waves done reading A tile
  char* h0 = smem;  // [32][128] bf16, swizzled, rowstride 256
#pragma unroll
  for (int mt = 0; mt < 2; ++mt)
#pragma unroll
    for (int tt = 0; tt < 2; ++tt)
#pragma unroll
      for (int j = 0; j < 4; ++j) {
        int row = 16 * mt + 4 * g + j;
        int col = 32 * w + 16 * tt + r;
        float v = 0.f;
        if (row < 30)
          v = gelu_f(acc[mt][tt][j] + vb[col] + bb0[tt]);
        int byte = row * 256 + col * 2;
        byte ^= (row & 7) << 4;
        *(unsigned short*)(h0 + byte) = f2bf(v);
      }
  __syncthreads();

  // ---- layer 1: [32x128] @ Wm1 ----
  char* h1 = smem + 8192;
  {
    f32x4 acc1[2][2];
#pragma unroll
    for (int mt = 0; mt < 2; ++mt)
#pragma unroll
      for (int tt = 0; tt < 2; ++tt) acc1[mt][tt] = zf;
#pragma unroll
    for (int s = 0; s < 4; ++s) {
      bf16x8 a[2];
#pragma unroll
      for (int mt = 0; mt < 2; ++mt) a[mt] = ld_afrag(h0, 16 * mt + r, 256, s, g);
#pragma unroll
      for (int tt = 0; tt < 2; ++tt) {
        bf16x8 b = ld_bfrag(pWm1, s, 2 * w + tt, 8, l);
#pragma unroll
        for (int mt = 0; mt < 2; ++mt)
          acc1[mt][tt] = __builtin_amdgcn_mfma_f32_16x16x32_bf16(a[mt], b, acc1[mt][tt], 0, 0, 0);
      }
    }
#pragma unroll
    for (int mt = 0; mt < 2; ++mt)
#pragma unroll
      for (int tt = 0; tt < 2; ++tt)
#pragma unroll
        for (int j = 0; j < 4; ++j) {
          int row = 16 * mt + 4 * g + j;
          int col = 32 * w + 16 * tt + r;
          float v = gelu_f(acc1[mt][tt][j] + bb1[tt]);
          int byte = row * 256 + col * 2;
          byte ^= (row & 7) << 4;
          *(unsigned short*)(h1 + byte) = f2bf(v);
        }
  }
  __syncthreads();

  // ---- layer 2: [32x128] @ Wm2; fragment-level masked row-sum -> Msum ----
  {
    f32x4 acc2[2][2];
#pragma unroll
    for (int mt = 0; mt < 2; ++mt)
#pragma unroll
      for (int tt = 0; tt < 2; ++tt) acc2[mt][tt] = zf;
#pragma unroll
    for (int s = 0; s < 4; ++s) {
      bf16x8 a[2];
#pragma unroll
      for (int mt = 0; mt < 2; ++mt) a[mt] = ld_afrag(h1, 16 * mt + r, 256, s, g);
#pragma unroll
      for (int tt = 0; tt < 2; ++tt) {
        bf16x8 b = ld_bfrag(pWm2, s, 2 * w + tt, 8, l);
#pragma unroll
        for (int mt = 0; mt < 2; ++mt)
          acc2[mt][tt] = __builtin_amdgcn_mfma_f32_16x16x32_bf16(a[mt], b, acc2[mt][tt], 0, 0, 0);
      }
    }
    float s0[2] = {0.f, 0.f};
#pragma unroll
    for (int mt = 0; mt < 2; ++mt)
#pragma unroll
      for (int tt = 0; tt < 2; ++tt)
#pragma unroll
        for (int j = 0; j < 4; ++j) {
          int row = 16 * mt + 4 * g + j;
          s0[tt] += (acc2[mt][tt][j] + bb2[tt]) * em_lds[row];  // pads em=0
        }
#pragma unroll
    for (int tt = 0; tt < 2; ++tt) {
      s0[tt] += __shfl_xor(s0[tt], 16);
      s0[tt] += __shfl_xor(s0[tt], 32);
    }
    if (g == 0) {
#pragma unroll
      for (int tt = 0; tt < 2; ++tt)
        Msum[(z * NN + n) * 128 + 32 * w + 16 * tt + r] = s0[tt];
    }
  }
}

// ---------------------------------------------------------------------------
// K2: 16 nodes/WG (grid 512). LN1 -> FFN (MFMA) -> LN2 -> out.
// LDS: V1f f32 [16][128] @0 (8K); A1 bf16 @8192 (4K, swz);
//      hb bf16 [16][512] @12288 (16K, swz); op f32 @8192 (8K, reuse). = 28672 B
// ---------------------------------------------------------------------------
__global__ __launch_bounds__(256, 2) void k2_ffn(
    const float* __restrict__ Vnew, const float* __restrict__ Msum,
    const u16x8* __restrict__ pWf0, const u16x8* __restrict__ pWf1,
    const float* __restrict__ bf0, const float* __restrict__ bf1,
    const float* __restrict__ gmn, const float* __restrict__ bmn,
    const float* __restrict__ gfn, const float* __restrict__ bfn,
    float* __restrict__ out) {
  extern __shared__ char smem[];
  float* V1f = (float*)smem;
  char* A1 = smem + 8192;
  char* hb = smem + 12288;
  const int tid = threadIdx.x;
  const int g0 = blockIdx.x * 16;

  // ---- LN1: V1 = LN(V_new + Msum); 16 lanes/row x 8 cols ----
  {
    int rr = tid >> 4, sub = tid & 15;
    int rowflat = g0 + rr;
    const float4* vn = (const float4*)(Vnew + rowflat * 128 + sub * 8);
    const float4* ms = (const float4*)(Msum + rowflat * 128 + sub * 8);
    float4 a0 = vn[0], a1 = vn[1], m0 = ms[0], m1 = ms[1];
    float v[8] = {a0.x + m0.x, a0.y + m0.y, a0.z + m0.z, a0.w + m0.w,
                  a1.x + m1.x, a1.y + m1.y, a1.z + m1.z, a1.w + m1.w};
    float s = 0.f, sq = 0.f;
#pragma unroll
    for (int i = 0; i < 8; ++i) { s += v[i]; sq += v[i] * v[i]; }
    s += __shfl_xor(s, 1);  sq += __shfl_xor(sq, 1);
    s += __shfl_xor(s, 2);  sq += __shfl_xor(sq, 2);
    s += __shfl_xor(s, 4);  sq += __shfl_xor(sq, 4);
    s += __shfl_xor(s, 8);  sq += __shfl_xor(sq, 8);
    float mean = s * (1.0f / 128.0f);
    float var = sq * (1.0f / 128.0f) - mean * mean;
    float inv = rsqrtf(var + 1e-5f);
    u16x4 h0v, h1v;
#pragma unroll
    for (int i = 0; i < 8; ++i) {
      int c = sub * 8 + i;
      float x = (v[i] - mean) * inv * gmn[c] + bmn[c];
      V1f[rr * 128 + c] = x;
      if (i < 4) h0v[i] = f2bf(x); else h1v[i - 4] = f2bf(x);
    }
    int byte = rr * 256 + ((sub * 16) ^ ((rr & 7) << 4));
    *(u16x4*)(A1 + byte) = h0v;
    *(u16x4*)(A1 + byte + 8) = h1v;
  }
  __syncthreads();

  const int w = tid >> 6, l = tid & 63;
  const int r = l & 15, g = l >> 4;
  const f32x4 zf = {0.f, 0.f, 0.f, 0.f};

  // ---- GEMM1: V1[16x128] @ W_f0[128x512], gelu -> hb ----
  {
    f32x4 acc[8];
#pragma unroll
    for (int tt = 0; tt < 8; ++tt) acc[tt] = zf;
#pragma unroll
    for (int s = 0; s < 4; ++s) {
      bf16x8 a = ld_afrag(A1, r, 256, s, g);
#pragma unroll
      for (int tt = 0; tt < 8; ++tt) {
        bf16x8 b = ld_bfrag(pWf0, s, 8 * w + tt, 32, l);
        acc[tt] = __builtin_amdgcn_mfma_f32_16x16x32_bf16(a, b, acc[tt], 0, 0, 0);
      }
    }
#pragma unroll
    for (int tt = 0; tt < 8; ++tt) {
      int col = 128 * w + 16 * tt + r;
      float bias = bf0[col];
#pragma unroll
      for (int j = 0; j < 4; ++j) {
        int row = 4 * g + j;
        float v = gelu_f(acc[tt][j] + bias);
        int byte = row * 1024 + col * 2;
        byte ^= (row & 7) << 4;
        *(unsigned short*)(hb + byte) = f2bf(v);
      }
    }
  }
  __syncthreads();

  // ---- GEMM2: hb[16x512] @ W_f1[512x128]; +residual +bias -> op ----
  {
    f32x4 acc2[2];
#pragma unroll
    for (int tt = 0; tt < 2; ++tt) acc2[tt] = zf;
    for (int s = 0; s < 16; ++s) {
      bf16x8 a = ld_afrag(hb, r, 1024, s, g);
#pragma unroll
      for (int tt = 0; tt < 2; ++tt) {
        bf16x8 b = ld_bfrag(pWf1, s, 2 * w + tt, 8, l);
        acc2[tt] = __builtin_amdgcn_mfma_f32_16x16x32_bf16(a, b, acc2[tt], 0, 0, 0);
      }
    }
    __syncthreads();  // all hb reads done; op overlays A1 + hb head
    float* op = (float*)(smem + 8192);
#pragma unroll
    for (int tt = 0; tt < 2; ++tt)
#pragma unroll
      for (int j = 0; j < 4; ++j) {
        int row = 4 * g + j;
        int col = 32 * w + 16 * tt + r;
        op[row * 128 + col] = V1f[row * 128 + col] + acc2[tt][j] + bf1[col];
      }
  }
  __syncthreads();

  // ---- LN2 + store ----
  {
    const float* op = (const float*)(smem + 8192);
    int rr = tid >> 4, sub = tid & 15;
    float v[8];
    float s = 0.f, sq = 0.f;
#pragma unroll
    for (int i = 0; i < 8; ++i) {
      v[i] = op[rr * 128 + sub * 8 + i];
      s += v[i]; sq += v[i] * v[i];
    }
    s += __shfl_xor(s, 1);  sq += __shfl_xor(sq, 1);
    s += __shfl_xor(s, 2);  sq += __shfl_xor(sq, 2);
    s += __shfl_xor(s, 4);  sq += __shfl_xor(sq, 4);
    s += __shfl_xor(s, 8);  sq += __shfl_xor(sq, 8);
    float mean = s * (1.0f / 128.0f);
    float var = sq * (1.0f / 128.0f) - mean * mean;
    float inv = rsqrtf(var + 1e-5f);
    int rowflat = g0 + rr;
    float* dst = out + rowflat * 128 + sub * 8;
    float4 o0, o1;
    int c = sub * 8;
    o0.x = (v[0] - mean) * inv * gfn[c + 0] + bfn[c + 0];
    o0.y = (v[1] - mean) * inv * gfn[c + 1] + bfn[c + 1];
    o0.z = (v[2] - mean) * inv * gfn[c + 2] + bfn[c + 2];
    o0.w = (v[3] - mean) * inv * gfn[c + 3] + bfn[c + 3];
    o1.x = (v[4] - mean) * inv * gfn[c + 4] + bfn[c + 4];
    o1.y = (v[5] - mean) * inv * gfn[c + 5] + bfn[c + 5];
    o1.z = (v[6] - mean) * inv * gfn[c + 6] + bfn[c + 6];
    o1.w = (v[7] - mean) * inv * gfn[c + 7] + bfn[c + 7];
    ((float4*)dst)[0] = o0;
    ((float4*)dst)[1] = o1;
  }
}

extern "C" void kernel_launch(void* const* d_in, const int* in_sizes, int n_in,
                              void* d_out, int out_size, void* d_ws, size_t ws_size,
                              hipStream_t stream) {
  const float* Vnew = (const float*)d_in[0];
  const float* Vold = (const float*)d_in[1];
  const float* E    = (const float*)d_in[2];
  const float* S    = (const float*)d_in[3];
  const int* Kidx   = (const int*)d_in[4];
  const void* emask = d_in[5];
  const void* amask = d_in[6];
  const float* Wm0 = (const float*)d_in[7];  const float* bm0 = (const float*)d_in[8];
  const float* Wm1 = (const float*)d_in[9];  const float* bm1 = (const float*)d_in[10];
  const float* Wm2 = (const float*)d_in[11]; const float* bm2 = (const float*)d_in[12];
  const float* gmn = (const float*)d_in[13]; const float* bmn = (const float*)d_in[14];
  const float* Wf0 = (const float*)d_in[15]; const float* bf0 = (const float*)d_in[16];
  const float* Wf1 = (const float*)d_in[17]; const float* bf1 = (const float*)d_in[18];
  const float* gfn = (const float*)d_in[19]; const float* bfn = (const float*)d_in[20];

  unsigned short* pack = (unsigned short*)d_ws;        // 458752 B
  const size_t need = 458752u + 4194304u + 4194304u;   // pack + VB + Msum
  bool useVB = ws_size >= need;
  float* VB = (float*)((char*)d_ws + 458752);
  float* Msum = useVB ? (float*)((char*)d_ws + 458752 + 4194304)
                      : (float*)((char*)d_ws + 458752);
  float* out = (float*)d_out;

  k0_pack<<<896, 256, 0, stream>>>(Wm0, Wm1, Wm2, Wf0, Wf1, pack);
  if (useVB) {
    kvb<<<512, 256, 0, stream>>>(Vnew, Wm0, VB);
    k1_edge_mlp<true><<<8192, 256, 25984, stream>>>(
        Vnew, Vold, E, S, Kidx, emask, amask, VB, Wm0,
        (const u16x8*)pack, (const u16x8*)(pack + 65536), (const u16x8*)(pack + 81920),
        bm0, bm1, bm2, Msum);
  } else {
    k1_edge_mlp<false><<<8192, 256, 25984, stream>>>(
        Vnew, Vold, E, S, Kidx, emask, amask, VB, Wm0,
        (const u16x8*)pack, (const u16x8*)(pack + 65536), (const u16x8*)(pack + 81920),
        bm0, bm1, bm2, Msum);
  }
  k2_ffn<<<512, 256, 28672, stream>>>(
      Vnew, Msum,
      (const u16x8*)(pack + 98304), (const u16x8*)(pack + 163840),
      bf0, bf1, gmn, bmn, gfn, bfn, out);
}